// Round 1
// baseline (6986.594 us; speedup 1.0000x reference)
//
#include <hip/hip_runtime.h>
#include <hip/hip_bf16.h>
#include <cstdint>

// ---------------- Threefry2x32 (JAX-compatible, 20 rounds) ----------------
__device__ __forceinline__ uint32_t rotl32(uint32_t v, int n) {
    return (v << n) | (v >> (32 - n));
}

__device__ __forceinline__ void threefry2x32(uint32_t k0, uint32_t k1,
                                             uint32_t x0, uint32_t x1,
                                             uint32_t& o0, uint32_t& o1) {
    uint32_t ks2 = 0x1BD11BDAu ^ k0 ^ k1;
    uint32_t v0 = x0 + k0, v1 = x1 + k1;
    // group 1: rotations (13,15,26,6)
    v0 += v1; v1 = rotl32(v1, 13); v1 ^= v0;
    v0 += v1; v1 = rotl32(v1, 15); v1 ^= v0;
    v0 += v1; v1 = rotl32(v1, 26); v1 ^= v0;
    v0 += v1; v1 = rotl32(v1, 6);  v1 ^= v0;
    v0 += k1; v1 += ks2 + 1u;
    // group 2: (17,29,16,24)
    v0 += v1; v1 = rotl32(v1, 17); v1 ^= v0;
    v0 += v1; v1 = rotl32(v1, 29); v1 ^= v0;
    v0 += v1; v1 = rotl32(v1, 16); v1 ^= v0;
    v0 += v1; v1 = rotl32(v1, 24); v1 ^= v0;
    v0 += ks2; v1 += k0 + 2u;
    // group 3
    v0 += v1; v1 = rotl32(v1, 13); v1 ^= v0;
    v0 += v1; v1 = rotl32(v1, 15); v1 ^= v0;
    v0 += v1; v1 = rotl32(v1, 26); v1 ^= v0;
    v0 += v1; v1 = rotl32(v1, 6);  v1 ^= v0;
    v0 += k0; v1 += k1 + 3u;
    // group 4
    v0 += v1; v1 = rotl32(v1, 17); v1 ^= v0;
    v0 += v1; v1 = rotl32(v1, 29); v1 ^= v0;
    v0 += v1; v1 = rotl32(v1, 16); v1 ^= v0;
    v0 += v1; v1 = rotl32(v1, 24); v1 ^= v0;
    v0 += k1; v1 += ks2 + 4u;
    // group 5
    v0 += v1; v1 = rotl32(v1, 13); v1 ^= v0;
    v0 += v1; v1 = rotl32(v1, 15); v1 ^= v0;
    v0 += v1; v1 = rotl32(v1, 26); v1 ^= v0;
    v0 += v1; v1 = rotl32(v1, 6);  v1 ^= v0;
    v0 += ks2; v1 += k0 + 5u;
    o0 = v0; o1 = v1;
}

__device__ __forceinline__ float bits_to_unit_float(uint32_t bits) {
    // XLA: bitcast((bits >> 9) | 0x3F800000) - 1.0f  -> [0,1)
    return __uint_as_float((bits >> 9) | 0x3F800000u) - 1.0f;
}

// XLA/Giles erfinv (f32)
__device__ __forceinline__ float erfinv_f(float x) {
    float w = -log1pf(-x * x);
    float p;
    if (w < 5.0f) {
        w = w - 2.5f;
        p = 2.81022636e-08f;
        p = fmaf(p, w, 3.43273939e-07f);
        p = fmaf(p, w, -3.5233877e-06f);
        p = fmaf(p, w, -4.39150654e-06f);
        p = fmaf(p, w, 0.00021858087f);
        p = fmaf(p, w, -0.00125372503f);
        p = fmaf(p, w, -0.00417768164f);
        p = fmaf(p, w, 0.246640727f);
        p = fmaf(p, w, 1.50140941f);
    } else {
        w = sqrtf(w) - 3.0f;
        p = -0.000200214257f;
        p = fmaf(p, w, 0.000100950558f);
        p = fmaf(p, w, 0.00134934322f);
        p = fmaf(p, w, -0.00367342844f);
        p = fmaf(p, w, 0.00573950773f);
        p = fmaf(p, w, -0.0076224613f);
        p = fmaf(p, w, 0.00943887047f);
        p = fmaf(p, w, 1.00167406f);
        p = fmaf(p, w, 2.83297682f);
    }
    return p * x;
}

// ---------------- Kernel 1: conv1 (6->64, 7x7, stride 4, pad 3) + relu ----------------
// out: [64,64,56,56]
__global__ __launch_bounds__(256) void conv1_relu(const float* __restrict__ x,
                                                  const float* __restrict__ W,
                                                  const float* __restrict__ bias,
                                                  float* __restrict__ out) {
    int idx = blockIdx.x * 256 + threadIdx.x;     // total 64*64*56*56 = 12,845,056
    int ow = idx % 56; int t = idx / 56;
    int oh = t % 56; t /= 56;
    int oc = t % 64; int b = t / 64;
    float acc = bias[oc];
    int ih0 = oh * 4 - 3, iw0 = ow * 4 - 3;
    const float* xb = x + (size_t)b * 6 * 224 * 224;
    const float* wc = W + oc * 6 * 49;
    for (int ic = 0; ic < 6; ic++) {
        const float* xc = xb + ic * 224 * 224;
        const float* wic = wc + ic * 49;
        #pragma unroll
        for (int kh = 0; kh < 7; kh++) {
            int ih = ih0 + kh;
            if ((unsigned)ih >= 224u) continue;
            #pragma unroll
            for (int kw = 0; kw < 7; kw++) {
                int iw = iw0 + kw;
                if ((unsigned)iw >= 224u) continue;
                acc = fmaf(xc[ih * 224 + iw], wic[kh * 7 + kw], acc);
            }
        }
    }
    out[idx] = fmaxf(acc, 0.0f);
}

// ---------------- Kernel 2: conv2 (64->256, 3x3, stride 2, pad 1) + relu + global mean --------
// block = (b, oc), pooled: [64,256]
__global__ __launch_bounds__(256) void conv2_pool(const float* __restrict__ h1,
                                                  const float* __restrict__ W2,
                                                  const float* __restrict__ b2,
                                                  float* __restrict__ pooled) {
    int oc = blockIdx.x % 256;
    int b  = blockIdx.x / 256;
    __shared__ float wsm[576];   // 64*3*3
    for (int i = threadIdx.x; i < 576; i += 256) wsm[i] = W2[oc * 576 + i];
    __syncthreads();
    float bias = b2[oc];
    const float* in = h1 + (size_t)b * 64 * 56 * 56;
    float local = 0.0f;
    for (int p = threadIdx.x; p < 784; p += 256) {
        int oh = p / 28, ow = p % 28;
        int ih0 = oh * 2 - 1, iw0 = ow * 2 - 1;
        float acc = bias;
        for (int ic = 0; ic < 64; ic++) {
            const float* xc = in + ic * 3136;  // 56*56
            const float* wc = wsm + ic * 9;
            #pragma unroll
            for (int kh = 0; kh < 3; kh++) {
                int ih = ih0 + kh;
                if ((unsigned)ih >= 56u) continue;
                #pragma unroll
                for (int kw = 0; kw < 3; kw++) {
                    int iw = iw0 + kw;
                    if ((unsigned)iw >= 56u) continue;
                    acc = fmaf(xc[ih * 56 + iw], wc[kh * 3 + kw], acc);
                }
            }
        }
        local += fmaxf(acc, 0.0f);
    }
    __shared__ float red[256];
    red[threadIdx.x] = local;
    __syncthreads();
    for (int s = 128; s > 0; s >>= 1) {
        if (threadIdx.x < s) red[threadIdx.x] += red[threadIdx.x + s];
        __syncthreads();
    }
    if (threadIdx.x == 0) pooled[b * 256 + oc] = red[0] / 784.0f;
}

// ---------------- Kernel 3: h = pooled @ Wh + bh  ([64,256]@[256,512]) ----------------
__global__ __launch_bounds__(512) void fc_h(const float* __restrict__ pooled,
                                            const float* __restrict__ Wh,
                                            const float* __restrict__ bh,
                                            float* __restrict__ h) {
    int b = blockIdx.x;
    int j = threadIdx.x;  // 512
    __shared__ float ps[256];
    if (threadIdx.x < 256) ps[threadIdx.x] = pooled[b * 256 + threadIdx.x];
    __syncthreads();
    float acc = bh[j];
    for (int i = 0; i < 256; i++) acc = fmaf(ps[i], Wh[i * 512 + j], acc);
    h[b * 512 + j] = acc;
}

// ---------------- Kernel 4: mu (normalized) + kappa; writes into d_out ----------------
// d_out layout: out[0:448], mu[448:2496], kappa[2496:2560]
__global__ __launch_bounds__(64) void mu_kappa(const float* __restrict__ h,
                                               const float* __restrict__ Wmu,
                                               const float* __restrict__ bmu,
                                               const float* __restrict__ Wk,
                                               const float* __restrict__ bk,
                                               float* __restrict__ out) {
    int b = blockIdx.x;
    int tid = threadIdx.x;
    __shared__ float hs[512];
    __shared__ float ms[32];
    __shared__ float norm;
    for (int i = tid; i < 512; i += 64) hs[i] = h[b * 512 + i];
    __syncthreads();
    if (tid < 32) {
        float acc = bmu[tid];
        for (int j = 0; j < 512; j++) acc = fmaf(hs[j], Wmu[j * 32 + tid], acc);
        ms[tid] = acc;
    } else if (tid == 32) {
        float acc = bk[0];
        for (int j = 0; j < 512; j++) acc = fmaf(hs[j], Wk[j], acc);
        // softplus = logaddexp(x, 0) = max(x,0) + log1p(exp(-|x|))
        float sp = fmaxf(acc, 0.0f) + log1pf(expf(-fabsf(acc)));
        out[2496 + b] = sp + 1.0f;
    }
    __syncthreads();
    if (tid == 0) {
        float ss = 0.0f;
        for (int k = 0; k < 32; k++) ss += ms[k] * ms[k];
        norm = sqrtf(fmaxf(ss, 1e-24f));
    }
    __syncthreads();
    if (tid < 32) out[448 + b * 32 + tid] = ms[tid] / norm;
}

// ---------------- Kernel 5: Wood vMF sampling (JAX threefry bit-exact) ----------------
// mu read from d_out+448, kappa from d_out+2496; z written to ws
__global__ __launch_bounds__(64) void vmf_sample(const float* __restrict__ mu,
                                                 const float* __restrict__ kap,
                                                 float* __restrict__ z) {
    int b = threadIdx.x;  // 64 threads, 1 block
    if (b >= 64) return;

    // root key = key(42) -> [0, 42]; split -> k_w, k_v
    uint32_t kw0, kw1, kv0, kv1;
    {
        uint32_t y00, y01, y10, y11;
        threefry2x32(0u, 42u, 0u, 2u, y00, y01);  // pair (0,2)
        threefry2x32(0u, 42u, 1u, 3u, y10, y11);  // pair (1,3)
        kw0 = y00; kw1 = y10;   // first row of reshape(2,2)
        kv0 = y01; kv1 = y11;   // second row
    }

    float kappa = kap[b];
    float w = 0.0f;
    bool accepted = false;
    uint32_t p = (uint32_t)(b & 31);
    #pragma unroll 1
    for (int i = 0; i < 10; i++) {
        uint32_t k10, k11, k20, k21, y0, y1;
        threefry2x32(kw0, kw1, 0u, (uint32_t)(2 * i), k10, k11);      // fold_in(k_w, 2i)
        threefry2x32(kw0, kw1, 0u, (uint32_t)(2 * i + 1), k20, k21);  // fold_in(k_w, 2i+1)
        threefry2x32(k10, k11, p, 32u + p, y0, y1);
        uint32_t bits = (b < 32) ? y0 : y1;
        float u1 = bits_to_unit_float(bits);
        float wc = 2.0f * u1 - 1.0f;
        float om = fmaxf(1.0f - wc * wc, 1e-40f);
        float logp = kappa * wc + 14.5f * logf(om);   // 0.5*(alpha-2)=14.5, alpha=31
        threefry2x32(k20, k21, p, 32u + p, y0, y1);
        bits = (b < 32) ? y0 : y1;
        float u2 = bits_to_unit_float(bits);
        float logr = logf(u2 + 1e-40f);
        bool newly = (logr + kappa <= logp) && !accepted;
        if (newly) w = wc;
        accepted = accepted || newly;
    }
    w = fminf(fmaxf(w, -1.0f), 1.0f);

    // v = normalize(normal(k_v, (64,31)))
    float v[31];
    float ss = 0.0f;
    const float LO = -0.99999994f;  // nextafter(-1,0); (1.0 - LO) rounds to 2.0f in f32 (XLA-equal)
    #pragma unroll 1
    for (int j = 0; j < 31; j++) {
        int idx = b * 31 + j;
        int word = (idx >= 992);
        uint32_t pp = (uint32_t)(word ? idx - 992 : idx);
        uint32_t y0, y1;
        threefry2x32(kv0, kv1, pp, 992u + pp, y0, y1);
        uint32_t bits = word ? y1 : y0;
        float f = bits_to_unit_float(bits);
        float u = fmaxf(LO, f * 2.0f + LO);
        float val = 1.41421356f * erfinv_f(u);
        v[j] = val;
        ss += val * val;
    }
    float vinv = 1.0f / sqrtf(fmaxf(ss, 1e-24f));
    float st = sqrtf(fmaxf(1.0f - w * w, 1e-40f));

    float zt[32];
    #pragma unroll
    for (int j = 0; j < 31; j++) zt[j] = st * (v[j] * vinv);
    zt[31] = w;

    // Householder: u = normalize(e_d - mu); z = zt - 2 (zt.u) u
    float uv[32];
    float us = 0.0f;
    #pragma unroll
    for (int k = 0; k < 32; k++) {
        float m = mu[b * 32 + k];
        float e = (k == 31) ? 1.0f : 0.0f;
        float t = e - m;
        uv[k] = t;
        us += t * t;
    }
    float un = sqrtf(fmaxf(us, 1e-24f));
    float dot = 0.0f;
    #pragma unroll
    for (int k = 0; k < 32; k++) {
        uv[k] = uv[k] / un;
        dot += zt[k] * uv[k];
    }
    #pragma unroll
    for (int k = 0; k < 32; k++) z[b * 32 + k] = zt[k] - 2.0f * dot * uv[k];
}

// ---------------- Kernel 6: MLP head (32->512->512->32->7), writes out[0:448] ----------------
__global__ __launch_bounds__(512) void mlp_head(const float* __restrict__ z,
                                                const float* __restrict__ M1, const float* __restrict__ bM1,
                                                const float* __restrict__ M2, const float* __restrict__ bM2,
                                                const float* __restrict__ M3, const float* __restrict__ bM3,
                                                const float* __restrict__ M4, const float* __restrict__ bM4,
                                                float* __restrict__ out) {
    int b = blockIdx.x;
    int tid = threadIdx.x;  // 512
    __shared__ float zs[32], y1[512], y2[512], y3[32];
    if (tid < 32) zs[tid] = z[b * 32 + tid];
    __syncthreads();
    float acc = bM1[tid];
    #pragma unroll
    for (int k = 0; k < 32; k++) acc = fmaf(zs[k], M1[k * 512 + tid], acc);
    y1[tid] = fmaxf(acc, 0.0f);
    __syncthreads();
    acc = bM2[tid];
    for (int k = 0; k < 512; k++) acc = fmaf(y1[k], M2[k * 512 + tid], acc);
    y2[tid] = fmaxf(acc, 0.0f);
    __syncthreads();
    if (tid < 32) {
        acc = bM3[tid];
        for (int k = 0; k < 512; k++) acc = fmaf(y2[k], M3[k * 32 + tid], acc);
        y3[tid] = fmaxf(acc, 0.0f);
    }
    __syncthreads();
    if (tid < 7) {
        acc = bM4[tid];
        #pragma unroll
        for (int k = 0; k < 32; k++) acc = fmaf(y3[k], M4[k * 7 + tid], acc);
        out[b * 7 + tid] = acc;
    }
}

extern "C" void kernel_launch(void* const* d_in, const int* in_sizes, int n_in,
                              void* d_out, int out_size, void* d_ws, size_t ws_size,
                              hipStream_t stream) {
    const float* x   = (const float*)d_in[0];
    const float* W1  = (const float*)d_in[1];
    const float* b1  = (const float*)d_in[2];
    const float* W2  = (const float*)d_in[3];
    const float* b2  = (const float*)d_in[4];
    const float* Wh  = (const float*)d_in[5];
    const float* bh  = (const float*)d_in[6];
    const float* Wmu = (const float*)d_in[7];
    const float* bmu = (const float*)d_in[8];
    const float* Wk  = (const float*)d_in[9];
    const float* bk  = (const float*)d_in[10];
    const float* M1  = (const float*)d_in[11];
    const float* bM1 = (const float*)d_in[12];
    const float* M2  = (const float*)d_in[13];
    const float* bM2 = (const float*)d_in[14];
    const float* M3  = (const float*)d_in[15];
    const float* bM3 = (const float*)d_in[16];
    const float* M4  = (const float*)d_in[17];
    const float* bM4 = (const float*)d_in[18];

    float* out = (float*)d_out;
    float* ws  = (float*)d_ws;

    // workspace layout (floats)
    float* c1     = ws;                       // 64*64*56*56 = 12,845,056
    float* pooled = ws + 12845056;            // 64*256
    float* h      = pooled + 16384;           // 64*512
    float* z      = h + 32768;                // 64*32

    conv1_relu<<<50176, 256, 0, stream>>>(x, W1, b1, c1);
    conv2_pool<<<16384, 256, 0, stream>>>(c1, W2, b2, pooled);
    fc_h<<<64, 512, 0, stream>>>(pooled, Wh, bh, h);
    mu_kappa<<<64, 64, 0, stream>>>(h, Wmu, bmu, Wk, bk, out);
    vmf_sample<<<1, 64, 0, stream>>>(out + 448, out + 2496, z);
    mlp_head<<<64, 512, 0, stream>>>(z, M1, bM1, M2, bM2, M3, bM3, M4, bM4, out);
}

// Round 2
// 642.610 us; speedup vs baseline: 10.8722x; 10.8722x over previous
//
#include <hip/hip_runtime.h>
#include <hip/hip_bf16.h>
#include <cstdint>

// ---------------- Threefry2x32 (JAX-compatible, 20 rounds) ----------------
__device__ __forceinline__ uint32_t rotl32(uint32_t v, int n) {
    return (v << n) | (v >> (32 - n));
}

__device__ __forceinline__ void threefry2x32(uint32_t k0, uint32_t k1,
                                             uint32_t x0, uint32_t x1,
                                             uint32_t& o0, uint32_t& o1) {
    uint32_t ks2 = 0x1BD11BDAu ^ k0 ^ k1;
    uint32_t v0 = x0 + k0, v1 = x1 + k1;
    v0 += v1; v1 = rotl32(v1, 13); v1 ^= v0;
    v0 += v1; v1 = rotl32(v1, 15); v1 ^= v0;
    v0 += v1; v1 = rotl32(v1, 26); v1 ^= v0;
    v0 += v1; v1 = rotl32(v1, 6);  v1 ^= v0;
    v0 += k1; v1 += ks2 + 1u;
    v0 += v1; v1 = rotl32(v1, 17); v1 ^= v0;
    v0 += v1; v1 = rotl32(v1, 29); v1 ^= v0;
    v0 += v1; v1 = rotl32(v1, 16); v1 ^= v0;
    v0 += v1; v1 = rotl32(v1, 24); v1 ^= v0;
    v0 += ks2; v1 += k0 + 2u;
    v0 += v1; v1 = rotl32(v1, 13); v1 ^= v0;
    v0 += v1; v1 = rotl32(v1, 15); v1 ^= v0;
    v0 += v1; v1 = rotl32(v1, 26); v1 ^= v0;
    v0 += v1; v1 = rotl32(v1, 6);  v1 ^= v0;
    v0 += k0; v1 += k1 + 3u;
    v0 += v1; v1 = rotl32(v1, 17); v1 ^= v0;
    v0 += v1; v1 = rotl32(v1, 29); v1 ^= v0;
    v0 += v1; v1 = rotl32(v1, 16); v1 ^= v0;
    v0 += v1; v1 = rotl32(v1, 24); v1 ^= v0;
    v0 += k1; v1 += ks2 + 4u;
    v0 += v1; v1 = rotl32(v1, 13); v1 ^= v0;
    v0 += v1; v1 = rotl32(v1, 15); v1 ^= v0;
    v0 += v1; v1 = rotl32(v1, 26); v1 ^= v0;
    v0 += v1; v1 = rotl32(v1, 6);  v1 ^= v0;
    v0 += ks2; v1 += k0 + 5u;
    o0 = v0; o1 = v1;
}

__device__ __forceinline__ float bits_to_unit_float(uint32_t bits) {
    return __uint_as_float((bits >> 9) | 0x3F800000u) - 1.0f;
}

__device__ __forceinline__ float erfinv_f(float x) {
    float w = -log1pf(-x * x);
    float p;
    if (w < 5.0f) {
        w = w - 2.5f;
        p = 2.81022636e-08f;
        p = fmaf(p, w, 3.43273939e-07f);
        p = fmaf(p, w, -3.5233877e-06f);
        p = fmaf(p, w, -4.39150654e-06f);
        p = fmaf(p, w, 0.00021858087f);
        p = fmaf(p, w, -0.00125372503f);
        p = fmaf(p, w, -0.00417768164f);
        p = fmaf(p, w, 0.246640727f);
        p = fmaf(p, w, 1.50140941f);
    } else {
        w = sqrtf(w) - 3.0f;
        p = -0.000200214257f;
        p = fmaf(p, w, 0.000100950558f);
        p = fmaf(p, w, 0.00134934322f);
        p = fmaf(p, w, -0.00367342844f);
        p = fmaf(p, w, 0.00573950773f);
        p = fmaf(p, w, -0.0076224613f);
        p = fmaf(p, w, 0.00943887047f);
        p = fmaf(p, w, 1.00167406f);
        p = fmaf(p, w, 2.83297682f);
    }
    return p * x;
}

// ---------------- Kernel 0: transpose weights to [p][oc] layout ----------------
// W1 [64][294] -> W1T [294][64]; W2 [256][576] -> W2T [576][256]
__global__ __launch_bounds__(256) void transpose_weights(const float* __restrict__ W1,
                                                         const float* __restrict__ W2,
                                                         float* __restrict__ W1T,
                                                         float* __restrict__ W2T) {
    int i = blockIdx.x * 256 + threadIdx.x;
    if (i < 18816) {
        int oc = i / 294, p = i % 294;
        W1T[p * 64 + oc] = W1[i];
    }
    if (i < 147456) {
        int oc = i / 576, p = i % 576;
        W2T[p * 256 + oc] = W2[i];
    }
}

// ---------------- Kernel 1: conv1 (6->64, 7x7, s4, p3) + relu, register-tiled ------------
// block: 32 oc x 4 oh x 56 ow; thread: 4 oc x 7 ow. grid: 64 b * 14 ohT * 2 ocT = 1792
__global__ __launch_bounds__(256) void conv1_tiled(const float* __restrict__ x,
                                                   const float* __restrict__ W1T,
                                                   const float* __restrict__ b1,
                                                   float* __restrict__ out) {
    int bid = blockIdx.x;
    int ocT = bid & 1;
    int ohT = (bid >> 1) % 14;
    int b   = bid / 28;
    int tid = threadIdx.x;
    int ocg = tid & 7;          // 8 groups of 4 oc
    int owg = (tid >> 3) & 7;   // 8 groups of 7 ow
    int ohh = tid >> 6;         // 4 rows

    // stage weights: w1s[p][32] for oc half-tile, transposed layout
    __shared__ __align__(16) float w1s[294 * 32];   // 37.6 KB
    for (int idx = tid; idx < 9408; idx += 256) {
        int p = idx >> 5, ocl = idx & 31;
        w1s[idx] = W1T[p * 64 + ocT * 32 + ocl];
    }
    __syncthreads();

    int oh = ohT * 4 + ohh;          // wave-uniform (ohh = tid>>6)
    int ih0 = oh * 4 - 3;
    int iwb = 28 * owg - 3;          // iw = iwb + 4*j + kw

    float acc[4][7];
    #pragma unroll
    for (int q = 0; q < 4; ++q)
        #pragma unroll
        for (int j = 0; j < 7; ++j) acc[q][j] = 0.0f;

    const float* xb = x + (size_t)b * 6 * 224 * 224;
    for (int ic = 0; ic < 6; ++ic) {
        const float* xc = xb + ic * 50176;
        #pragma unroll
        for (int kh = 0; kh < 7; ++kh) {
            int ih = ih0 + kh;
            if ((unsigned)ih >= 224u) continue;   // wave-uniform branch
            const float* xrow = xc + ih * 224;
            int pbase = ic * 49 + kh * 7;
            #pragma unroll
            for (int kw = 0; kw < 7; ++kw) {
                float4 w4 = *reinterpret_cast<const float4*>(&w1s[(pbase + kw) * 32 + 4 * ocg]);
                #pragma unroll
                for (int j = 0; j < 7; ++j) {
                    int iw = iwb + 4 * j + kw;
                    float xv = ((unsigned)iw < 224u) ? xrow[iw] : 0.0f;
                    acc[0][j] = fmaf(xv, w4.x, acc[0][j]);
                    acc[1][j] = fmaf(xv, w4.y, acc[1][j]);
                    acc[2][j] = fmaf(xv, w4.z, acc[2][j]);
                    acc[3][j] = fmaf(xv, w4.w, acc[3][j]);
                }
            }
        }
    }

    int oc0 = ocT * 32 + 4 * ocg;
    #pragma unroll
    for (int q = 0; q < 4; ++q) {
        float bias = b1[oc0 + q];
        float* orow = out + (((size_t)b * 64 + oc0 + q) * 56 + oh) * 56 + 7 * owg;
        #pragma unroll
        for (int j = 0; j < 7; ++j) orow[j] = fmaxf(acc[q][j] + bias, 0.0f);
    }
}

// ---------------- Kernel 2: conv2 (64->256, 3x3, s2, p1) + relu + partial pool ----------
// block: 64 oc x 4 oh x 28 ow; thread: 4 oc x 7 ow. grid: 64 b * 7 ohT * 4 ocT = 1792
// ic processed in 8 chunks of 8; input chunk + weight chunk staged in LDS.
__global__ __launch_bounds__(256) void conv2_tiled(const float* __restrict__ c1,
                                                   const float* __restrict__ W2T,
                                                   const float* __restrict__ b2,
                                                   float* __restrict__ part2) {
    int bid = blockIdx.x;
    int ocT = bid & 3;
    int ohT = (bid >> 2) % 7;
    int b   = bid / 28;
    int tid = threadIdx.x;
    int ocg = tid & 15;          // 16 groups of 4 oc
    int owg = (tid >> 4) & 3;    // 4 groups of 7 ow
    int ohh = tid >> 6;          // 4 rows

    __shared__ __align__(16) float in2[8 * 9 * 58];     // 16.7 KB
    __shared__ __align__(16) float w2s[8 * 9 * 64];     // 18.4 KB
    __shared__ float red[4 * 16 * 64];                  // 4 KB   (ocl x 16 partials)

    int ihb = 8 * ohT - 1;
    int cb = 14 * owg;           // c = cb + 2*j + kw

    float acc[4][7];
    #pragma unroll
    for (int q = 0; q < 4; ++q)
        #pragma unroll
        for (int j = 0; j < 7; ++j) acc[q][j] = 0.0f;

    for (int chunk = 0; chunk < 8; ++chunk) {
        int ic0 = chunk * 8;
        __syncthreads();
        // stage input: [8 ic][9 rows][58 cols], zero-padded
        for (int idx = tid; idx < 4176; idx += 256) {
            int icl = idx / 522;
            int rem = idx % 522;
            int r = rem / 58, c = rem % 58;
            int ih = ihb + r, iw = c - 1;
            float v = 0.0f;
            if ((unsigned)ih < 56u && (unsigned)iw < 56u)
                v = c1[(((size_t)b * 64 + ic0 + icl) * 56 + ih) * 56 + iw];
            in2[idx] = v;
        }
        // stage weights: w2s[pl][64]
        for (int idx = tid; idx < 4608; idx += 256) {
            int pl = idx >> 6, ocl = idx & 63;
            w2s[idx] = W2T[(ic0 * 9 + pl) * 256 + ocT * 64 + ocl];
        }
        __syncthreads();

        for (int icl = 0; icl < 8; ++icl) {
            #pragma unroll
            for (int kh = 0; kh < 3; ++kh) {
                const float* irow = &in2[(icl * 9 + 2 * ohh + kh) * 58];
                int pbase = icl * 9 + kh * 3;
                #pragma unroll
                for (int kw = 0; kw < 3; ++kw) {
                    float4 w4 = *reinterpret_cast<const float4*>(&w2s[(pbase + kw) * 64 + 4 * ocg]);
                    #pragma unroll
                    for (int j = 0; j < 7; ++j) {
                        float xv = irow[cb + 2 * j + kw];
                        acc[0][j] = fmaf(xv, w4.x, acc[0][j]);
                        acc[1][j] = fmaf(xv, w4.y, acc[1][j]);
                        acc[2][j] = fmaf(xv, w4.z, acc[2][j]);
                        acc[3][j] = fmaf(xv, w4.w, acc[3][j]);
                    }
                }
            }
        }
    }

    // bias + relu + per-thread partial sum, then block reduce (fixed order)
    int oc0 = ocT * 64 + 4 * ocg;
    __syncthreads();
    #pragma unroll
    for (int q = 0; q < 4; ++q) {
        float bias = b2[oc0 + q];
        float s = 0.0f;
        #pragma unroll
        for (int j = 0; j < 7; ++j) s += fmaxf(acc[q][j] + bias, 0.0f);
        red[(4 * ocg + q) * 16 + owg * 4 + ohh] = s;
    }
    __syncthreads();
    if (tid < 64) {
        float s = 0.0f;
        #pragma unroll
        for (int i = 0; i < 16; ++i) s += red[tid * 16 + i];
        part2[((size_t)ohT * 64 + b) * 256 + ocT * 64 + tid] = s;
    }
}

// ---------------- Kernel 2b: fixed-order pooling reduce ----------------
__global__ __launch_bounds__(256) void pool_reduce(const float* __restrict__ part2,
                                                   float* __restrict__ pooled) {
    int b = blockIdx.x, oc = threadIdx.x;
    float s = 0.0f;
    #pragma unroll
    for (int t = 0; t < 7; ++t) s += part2[((size_t)t * 64 + b) * 256 + oc];
    pooled[b * 256 + oc] = s / 784.0f;
}

// ---------------- Kernel 3: h = pooled @ Wh + bh ----------------
__global__ __launch_bounds__(512) void fc_h(const float* __restrict__ pooled,
                                            const float* __restrict__ Wh,
                                            const float* __restrict__ bh,
                                            float* __restrict__ h) {
    int b = blockIdx.x;
    int j = threadIdx.x;
    __shared__ float ps[256];
    if (threadIdx.x < 256) ps[threadIdx.x] = pooled[b * 256 + threadIdx.x];
    __syncthreads();
    float acc = bh[j];
    for (int i = 0; i < 256; i++) acc = fmaf(ps[i], Wh[i * 512 + j], acc);
    h[b * 512 + j] = acc;
}

// ---------------- Kernel 4: mu (normalized) + kappa ----------------
// d_out layout: out[0:448], mu[448:2496], kappa[2496:2560]
__global__ __launch_bounds__(64) void mu_kappa(const float* __restrict__ h,
                                               const float* __restrict__ Wmu,
                                               const float* __restrict__ bmu,
                                               const float* __restrict__ Wk,
                                               const float* __restrict__ bk,
                                               float* __restrict__ out) {
    int b = blockIdx.x;
    int tid = threadIdx.x;
    __shared__ float hs[512];
    __shared__ float ms[32];
    __shared__ float norm;
    for (int i = tid; i < 512; i += 64) hs[i] = h[b * 512 + i];
    __syncthreads();
    if (tid < 32) {
        float acc = bmu[tid];
        for (int j = 0; j < 512; j++) acc = fmaf(hs[j], Wmu[j * 32 + tid], acc);
        ms[tid] = acc;
    } else if (tid == 32) {
        float acc = bk[0];
        for (int j = 0; j < 512; j++) acc = fmaf(hs[j], Wk[j], acc);
        float sp = fmaxf(acc, 0.0f) + log1pf(expf(-fabsf(acc)));
        out[2496 + b] = sp + 1.0f;
    }
    __syncthreads();
    if (tid == 0) {
        float ss = 0.0f;
        for (int k = 0; k < 32; k++) ss += ms[k] * ms[k];
        norm = sqrtf(fmaxf(ss, 1e-24f));
    }
    __syncthreads();
    if (tid < 32) out[448 + b * 32 + tid] = ms[tid] / norm;
}

// ---------------- Kernel 5: Wood vMF sampling (JAX threefry bit-exact) ----------------
__global__ __launch_bounds__(64) void vmf_sample(const float* __restrict__ mu,
                                                 const float* __restrict__ kap,
                                                 float* __restrict__ z) {
    int b = threadIdx.x;
    if (b >= 64) return;

    uint32_t kw0, kw1, kv0, kv1;
    {
        uint32_t y00, y01, y10, y11;
        threefry2x32(0u, 42u, 0u, 2u, y00, y01);
        threefry2x32(0u, 42u, 1u, 3u, y10, y11);
        kw0 = y00; kw1 = y10;
        kv0 = y01; kv1 = y11;
    }

    float kappa = kap[b];
    float w = 0.0f;
    bool accepted = false;
    uint32_t p = (uint32_t)(b & 31);
    #pragma unroll 1
    for (int i = 0; i < 10; i++) {
        uint32_t k10, k11, k20, k21, y0, y1;
        threefry2x32(kw0, kw1, 0u, (uint32_t)(2 * i), k10, k11);
        threefry2x32(kw0, kw1, 0u, (uint32_t)(2 * i + 1), k20, k21);
        threefry2x32(k10, k11, p, 32u + p, y0, y1);
        uint32_t bits = (b < 32) ? y0 : y1;
        float u1 = bits_to_unit_float(bits);
        float wc = 2.0f * u1 - 1.0f;
        float om = fmaxf(1.0f - wc * wc, 1e-40f);
        float logp = kappa * wc + 14.5f * logf(om);
        threefry2x32(k20, k21, p, 32u + p, y0, y1);
        bits = (b < 32) ? y0 : y1;
        float u2 = bits_to_unit_float(bits);
        float logr = logf(u2 + 1e-40f);
        bool newly = (logr + kappa <= logp) && !accepted;
        if (newly) w = wc;
        accepted = accepted || newly;
    }
    w = fminf(fmaxf(w, -1.0f), 1.0f);

    float v[31];
    float ss = 0.0f;
    const float LO = -0.99999994f;
    #pragma unroll 1
    for (int j = 0; j < 31; j++) {
        int idx = b * 31 + j;
        int word = (idx >= 992);
        uint32_t pp = (uint32_t)(word ? idx - 992 : idx);
        uint32_t y0, y1;
        threefry2x32(kv0, kv1, pp, 992u + pp, y0, y1);
        uint32_t bits = word ? y1 : y0;
        float f = bits_to_unit_float(bits);
        float u = fmaxf(LO, f * 2.0f + LO);
        float val = 1.41421356f * erfinv_f(u);
        v[j] = val;
        ss += val * val;
    }
    float vinv = 1.0f / sqrtf(fmaxf(ss, 1e-24f));
    float st = sqrtf(fmaxf(1.0f - w * w, 1e-40f));

    float zt[32];
    #pragma unroll
    for (int j = 0; j < 31; j++) zt[j] = st * (v[j] * vinv);
    zt[31] = w;

    float uv[32];
    float us = 0.0f;
    #pragma unroll
    for (int k = 0; k < 32; k++) {
        float m = mu[b * 32 + k];
        float e = (k == 31) ? 1.0f : 0.0f;
        float t = e - m;
        uv[k] = t;
        us += t * t;
    }
    float un = sqrtf(fmaxf(us, 1e-24f));
    float dot = 0.0f;
    #pragma unroll
    for (int k = 0; k < 32; k++) {
        uv[k] = uv[k] / un;
        dot += zt[k] * uv[k];
    }
    #pragma unroll
    for (int k = 0; k < 32; k++) z[b * 32 + k] = zt[k] - 2.0f * dot * uv[k];
}

// ---------------- Kernel 6: MLP head (32->512->512->32->7) ----------------
__global__ __launch_bounds__(512) void mlp_head(const float* __restrict__ z,
                                                const float* __restrict__ M1, const float* __restrict__ bM1,
                                                const float* __restrict__ M2, const float* __restrict__ bM2,
                                                const float* __restrict__ M3, const float* __restrict__ bM3,
                                                const float* __restrict__ M4, const float* __restrict__ bM4,
                                                float* __restrict__ out) {
    int b = blockIdx.x;
    int tid = threadIdx.x;
    __shared__ float zs[32], y1[512], y2[512], y3[32];
    if (tid < 32) zs[tid] = z[b * 32 + tid];
    __syncthreads();
    float acc = bM1[tid];
    #pragma unroll
    for (int k = 0; k < 32; k++) acc = fmaf(zs[k], M1[k * 512 + tid], acc);
    y1[tid] = fmaxf(acc, 0.0f);
    __syncthreads();
    acc = bM2[tid];
    for (int k = 0; k < 512; k++) acc = fmaf(y1[k], M2[k * 512 + tid], acc);
    y2[tid] = fmaxf(acc, 0.0f);
    __syncthreads();
    if (tid < 32) {
        acc = bM3[tid];
        for (int k = 0; k < 512; k++) acc = fmaf(y2[k], M3[k * 32 + tid], acc);
        y3[tid] = fmaxf(acc, 0.0f);
    }
    __syncthreads();
    if (tid < 7) {
        acc = bM4[tid];
        #pragma unroll
        for (int k = 0; k < 32; k++) acc = fmaf(y3[k], M4[k * 7 + tid], acc);
        out[b * 7 + tid] = acc;
    }
}

extern "C" void kernel_launch(void* const* d_in, const int* in_sizes, int n_in,
                              void* d_out, int out_size, void* d_ws, size_t ws_size,
                              hipStream_t stream) {
    const float* x   = (const float*)d_in[0];
    const float* W1  = (const float*)d_in[1];
    const float* b1  = (const float*)d_in[2];
    const float* W2  = (const float*)d_in[3];
    const float* b2  = (const float*)d_in[4];
    const float* Wh  = (const float*)d_in[5];
    const float* bh  = (const float*)d_in[6];
    const float* Wmu = (const float*)d_in[7];
    const float* bmu = (const float*)d_in[8];
    const float* Wk  = (const float*)d_in[9];
    const float* bk  = (const float*)d_in[10];
    const float* M1  = (const float*)d_in[11];
    const float* bM1 = (const float*)d_in[12];
    const float* M2  = (const float*)d_in[13];
    const float* bM2 = (const float*)d_in[14];
    const float* M3  = (const float*)d_in[15];
    const float* bM3 = (const float*)d_in[16];
    const float* M4  = (const float*)d_in[17];
    const float* bM4 = (const float*)d_in[18];

    float* out = (float*)d_out;
    float* ws  = (float*)d_ws;

    // workspace layout (floats)
    float* W1T    = ws;                  // 18816
    float* W2T    = W1T + 18816;         // 147456
    float* c1     = W2T + 147456;        // 12845056
    float* part2  = c1 + 12845056;       // 7*64*256 = 114688
    float* pooled = part2 + 114688;      // 16384
    float* h      = pooled + 16384;      // 32768
    float* z      = h + 32768;           // 2048

    transpose_weights<<<576, 256, 0, stream>>>(W1, W2, W1T, W2T);
    conv1_tiled<<<1792, 256, 0, stream>>>(x, W1T, b1, c1);
    conv2_tiled<<<1792, 256, 0, stream>>>(c1, W2T, b2, part2);
    pool_reduce<<<64, 256, 0, stream>>>(part2, pooled);
    fc_h<<<64, 512, 0, stream>>>(pooled, Wh, bh, h);
    mu_kappa<<<64, 64, 0, stream>>>(h, Wmu, bmu, Wk, bk, out);
    vmf_sample<<<1, 64, 0, stream>>>(out + 448, out + 2496, z);
    mlp_head<<<64, 512, 0, stream>>>(z, M1, bM1, M2, bM2, M3, bM3, M4, bM4, out);
}

// Round 3
// 501.954 us; speedup vs baseline: 13.9188x; 1.2802x over previous
//
#include <hip/hip_runtime.h>
#include <hip/hip_bf16.h>
#include <cstdint>

// ---------------- Threefry2x32 (JAX-compatible, 20 rounds) ----------------
__device__ __forceinline__ uint32_t rotl32(uint32_t v, int n) {
    return (v << n) | (v >> (32 - n));
}

__device__ __forceinline__ void threefry2x32(uint32_t k0, uint32_t k1,
                                             uint32_t x0, uint32_t x1,
                                             uint32_t& o0, uint32_t& o1) {
    uint32_t ks2 = 0x1BD11BDAu ^ k0 ^ k1;
    uint32_t v0 = x0 + k0, v1 = x1 + k1;
    v0 += v1; v1 = rotl32(v1, 13); v1 ^= v0;
    v0 += v1; v1 = rotl32(v1, 15); v1 ^= v0;
    v0 += v1; v1 = rotl32(v1, 26); v1 ^= v0;
    v0 += v1; v1 = rotl32(v1, 6);  v1 ^= v0;
    v0 += k1; v1 += ks2 + 1u;
    v0 += v1; v1 = rotl32(v1, 17); v1 ^= v0;
    v0 += v1; v1 = rotl32(v1, 29); v1 ^= v0;
    v0 += v1; v1 = rotl32(v1, 16); v1 ^= v0;
    v0 += v1; v1 = rotl32(v1, 24); v1 ^= v0;
    v0 += ks2; v1 += k0 + 2u;
    v0 += v1; v1 = rotl32(v1, 13); v1 ^= v0;
    v0 += v1; v1 = rotl32(v1, 15); v1 ^= v0;
    v0 += v1; v1 = rotl32(v1, 26); v1 ^= v0;
    v0 += v1; v1 = rotl32(v1, 6);  v1 ^= v0;
    v0 += k0; v1 += k1 + 3u;
    v0 += v1; v1 = rotl32(v1, 17); v1 ^= v0;
    v0 += v1; v1 = rotl32(v1, 29); v1 ^= v0;
    v0 += v1; v1 = rotl32(v1, 16); v1 ^= v0;
    v0 += v1; v1 = rotl32(v1, 24); v1 ^= v0;
    v0 += k1; v1 += ks2 + 4u;
    v0 += v1; v1 = rotl32(v1, 13); v1 ^= v0;
    v0 += v1; v1 = rotl32(v1, 15); v1 ^= v0;
    v0 += v1; v1 = rotl32(v1, 26); v1 ^= v0;
    v0 += v1; v1 = rotl32(v1, 6);  v1 ^= v0;
    v0 += ks2; v1 += k0 + 5u;
    o0 = v0; o1 = v1;
}

__device__ __forceinline__ float bits_to_unit_float(uint32_t bits) {
    return __uint_as_float((bits >> 9) | 0x3F800000u) - 1.0f;
}

__device__ __forceinline__ float erfinv_f(float x) {
    float w = -log1pf(-x * x);
    float p;
    if (w < 5.0f) {
        w = w - 2.5f;
        p = 2.81022636e-08f;
        p = fmaf(p, w, 3.43273939e-07f);
        p = fmaf(p, w, -3.5233877e-06f);
        p = fmaf(p, w, -4.39150654e-06f);
        p = fmaf(p, w, 0.00021858087f);
        p = fmaf(p, w, -0.00125372503f);
        p = fmaf(p, w, -0.00417768164f);
        p = fmaf(p, w, 0.246640727f);
        p = fmaf(p, w, 1.50140941f);
    } else {
        w = sqrtf(w) - 3.0f;
        p = -0.000200214257f;
        p = fmaf(p, w, 0.000100950558f);
        p = fmaf(p, w, 0.00134934322f);
        p = fmaf(p, w, -0.00367342844f);
        p = fmaf(p, w, 0.00573950773f);
        p = fmaf(p, w, -0.0076224613f);
        p = fmaf(p, w, 0.00943887047f);
        p = fmaf(p, w, 1.00167406f);
        p = fmaf(p, w, 2.83297682f);
    }
    return p * x;
}

// ---------------- W2 transpose: [256][576] -> [576][256], 32x32 LDS tiles ----------------
__global__ __launch_bounds__(256) void transpose_W2(const float* __restrict__ W2,
                                                    float* __restrict__ W2T) {
    __shared__ float t[32][33];
    int pT = blockIdx.x % 18;    // 576/32
    int oT = blockIdx.x / 18;    // 256/32
    int c = threadIdx.x & 31, r8 = threadIdx.x >> 5;  // r8: 0..7
    #pragma unroll
    for (int rr = 0; rr < 4; ++rr) {
        int oc = oT * 32 + r8 + 8 * rr;
        t[r8 + 8 * rr][c] = W2[oc * 576 + pT * 32 + c];
    }
    __syncthreads();
    #pragma unroll
    for (int rr = 0; rr < 4; ++rr) {
        int p = pT * 32 + r8 + 8 * rr;
        W2T[p * 256 + oT * 32 + c] = t[c][r8 + 8 * rr];
    }
}

// ---------------- conv1 (6->64, 7x7, s4, p3) + relu ----------------
// block: 32 oc x 8 oh x 56 ow; thread: 8 oc x 7 ow. grid = 64b * 7ohT * 2ocT = 896
__global__ __launch_bounds__(256) void conv1_tiled(const float* __restrict__ x,
                                                   const float* __restrict__ W1,
                                                   const float* __restrict__ b1,
                                                   float* __restrict__ out) {
    int bid = blockIdx.x;
    int ocT = bid & 1;
    int ohT = (bid >> 1) % 7;
    int b   = bid / 14;
    int tid = threadIdx.x;
    int ocg = tid & 3;           // 4 groups x 8 oc = 32 oc
    int owg = (tid >> 2) & 7;    // 8 groups x 7 ow = 56 ow
    int ohh = tid >> 5;          // 8 rows

    __shared__ __align__(16) float w1s[9408];   // [294][32], 37.6 KB
    for (int idx = tid; idx < 9408; idx += 256) {
        int p = idx >> 5, ocl = idx & 31;
        w1s[idx] = W1[(ocT * 32 + ocl) * 294 + p];
    }
    __syncthreads();

    int oh = ohT * 8 + ohh;
    int ih0 = oh * 4 - 3;
    int iwb = owg * 28 - 3;

    float acc[8][7];
    #pragma unroll
    for (int q = 0; q < 8; ++q)
        #pragma unroll
        for (int j = 0; j < 7; ++j) acc[q][j] = 0.0f;

    const float* xb = x + (size_t)b * 6 * 50176;
    #pragma unroll 1
    for (int ic = 0; ic < 6; ++ic) {
        const float* xc = xb + ic * 50176;
        #pragma unroll 1
        for (int kh = 0; kh < 7; ++kh) {
            int ih = ih0 + kh;
            bool rowok = ((unsigned)ih < 224u);
            const float* xrow = xc + ih * 224;
            float r[31];
            #pragma unroll
            for (int p = 0; p < 31; ++p) {
                int iw = iwb + p;
                r[p] = (rowok && (unsigned)iw < 224u) ? xrow[iw] : 0.0f;
            }
            int pb = ic * 49 + kh * 7;
            #pragma unroll
            for (int kw = 0; kw < 7; ++kw) {
                float4 wa = *reinterpret_cast<const float4*>(&w1s[(pb + kw) * 32 + 8 * ocg]);
                float4 wb = *reinterpret_cast<const float4*>(&w1s[(pb + kw) * 32 + 8 * ocg + 4]);
                #pragma unroll
                for (int j = 0; j < 7; ++j) {
                    float xv = r[4 * j + kw];
                    acc[0][j] = fmaf(xv, wa.x, acc[0][j]);
                    acc[1][j] = fmaf(xv, wa.y, acc[1][j]);
                    acc[2][j] = fmaf(xv, wa.z, acc[2][j]);
                    acc[3][j] = fmaf(xv, wa.w, acc[3][j]);
                    acc[4][j] = fmaf(xv, wb.x, acc[4][j]);
                    acc[5][j] = fmaf(xv, wb.y, acc[5][j]);
                    acc[6][j] = fmaf(xv, wb.z, acc[6][j]);
                    acc[7][j] = fmaf(xv, wb.w, acc[7][j]);
                }
            }
        }
    }

    int oc0 = ocT * 32 + 8 * ocg;
    #pragma unroll
    for (int q = 0; q < 8; ++q) {
        float bias = b1[oc0 + q];
        float* orow = out + (((size_t)b * 64 + oc0 + q) * 56 + oh) * 56 + 7 * owg;
        #pragma unroll
        for (int j = 0; j < 7; ++j) orow[j] = fmaxf(acc[q][j] + bias, 0.0f);
    }
}

// ---------------- conv2 (64->256, 3x3, s2, p1) + relu + partial pool ----------------
// block: 128 oc x 4 oh x 28 ow; thread: 8 oc (split 4+4 across row halves) x 7 ow.
// grid = 64b * 7ohT * 2ocT = 896
__global__ __launch_bounds__(256) void conv2_tiled(const float* __restrict__ c1,
                                                   const float* __restrict__ W2T,
                                                   const float* __restrict__ b2,
                                                   float* __restrict__ part2) {
    int bid = blockIdx.x;
    int ocT = bid & 1;
    int ohT = (bid >> 1) % 7;
    int b   = bid / 14;
    int tid = threadIdx.x;
    int ocg = tid & 15;          // 16 groups x 8 oc = 128 oc
    int owg = (tid >> 4) & 3;    // 4 groups x 7 ow = 28 ow
    int ohh = tid >> 6;          // 4 rows

    // smem: in2 [8][9][58] = 4176 | w2s [72][128] = 9216 ; red overlays front after compute
    __shared__ __align__(16) float smem[13392];   // 53.6 KB
    float* in2 = smem;
    float* w2s = smem + 4176;
    float* red = smem;

    int ihb = 8 * ohT - 1;
    int cb = owg * 14;

    float acc[8][7];
    #pragma unroll
    for (int q = 0; q < 8; ++q)
        #pragma unroll
        for (int j = 0; j < 7; ++j) acc[q][j] = 0.0f;

    #pragma unroll 1
    for (int chunk = 0; chunk < 8; ++chunk) {
        int ic0 = chunk * 8;
        __syncthreads();
        for (int idx = tid; idx < 4176; idx += 256) {
            int icl = idx / 522;
            int rem = idx % 522;
            int r = rem / 58, c = rem % 58;
            int ih = ihb + r, iw = c - 1;
            float v = 0.0f;
            if ((unsigned)ih < 56u && (unsigned)iw < 56u)
                v = c1[(((size_t)b * 64 + ic0 + icl) * 56 + ih) * 56 + iw];
            in2[idx] = v;
        }
        for (int idx = tid; idx < 9216; idx += 256) {
            int pl = idx >> 7, ocl = idx & 127;
            w2s[idx] = W2T[((size_t)(ic0 * 9 + pl)) * 256 + ocT * 128 + ocl];
        }
        __syncthreads();

        #pragma unroll 1
        for (int icl = 0; icl < 8; ++icl) {
            #pragma unroll
            for (int kh = 0; kh < 3; ++kh) {
                const float* rbase = &in2[(icl * 9 + 2 * ohh + kh) * 58 + cb];
                float r[15];
                #pragma unroll
                for (int pos = 0; pos < 15; ++pos) r[pos] = rbase[pos];
                int pb = icl * 9 + kh * 3;
                #pragma unroll
                for (int kw = 0; kw < 3; ++kw) {
                    float4 wa = *reinterpret_cast<const float4*>(&w2s[(pb + kw) * 128 + 4 * ocg]);
                    float4 wb = *reinterpret_cast<const float4*>(&w2s[(pb + kw) * 128 + 64 + 4 * ocg]);
                    #pragma unroll
                    for (int j = 0; j < 7; ++j) {
                        float xv = r[2 * j + kw];
                        acc[0][j] = fmaf(xv, wa.x, acc[0][j]);
                        acc[1][j] = fmaf(xv, wa.y, acc[1][j]);
                        acc[2][j] = fmaf(xv, wa.z, acc[2][j]);
                        acc[3][j] = fmaf(xv, wa.w, acc[3][j]);
                        acc[4][j] = fmaf(xv, wb.x, acc[4][j]);
                        acc[5][j] = fmaf(xv, wb.y, acc[5][j]);
                        acc[6][j] = fmaf(xv, wb.z, acc[6][j]);
                        acc[7][j] = fmaf(xv, wb.w, acc[7][j]);
                    }
                }
            }
        }
    }

    // bias + relu + per-thread 7-ow partial sums; block reduce (fixed order)
    __syncthreads();
    int sp = ohh * 4 + owg;      // 0..15
    #pragma unroll
    for (int q = 0; q < 8; ++q) {
        int ocl = (q < 4) ? (ocg * 4 + q) : (64 + ocg * 4 + (q - 4));
        float bias = b2[ocT * 128 + ocl];
        float s = 0.0f;
        #pragma unroll
        for (int j = 0; j < 7; ++j) s += fmaxf(acc[q][j] + bias, 0.0f);
        red[ocl * 16 + sp] = s;
    }
    __syncthreads();
    if (tid < 128) {
        float s = 0.0f;
        #pragma unroll
        for (int i = 0; i < 16; ++i) s += red[tid * 16 + i];
        part2[((size_t)ohT * 64 + b) * 256 + ocT * 128 + tid] = s;
    }
}

// ---------------- head: pool + fc_h + mu + kappa (fused) ----------------
// d_out layout: out[0:448], mu[448:2496], kappa[2496:2560]
__global__ __launch_bounds__(512) void head_fused(const float* __restrict__ part2,
                                                  const float* __restrict__ Wh,
                                                  const float* __restrict__ bh,
                                                  const float* __restrict__ Wmu,
                                                  const float* __restrict__ bmu,
                                                  const float* __restrict__ Wk,
                                                  const float* __restrict__ bk,
                                                  float* __restrict__ out) {
    int b = blockIdx.x, tid = threadIdx.x;
    __shared__ float ps[256], hs[512], ms[32], red2[512], kred[16];
    __shared__ float nrm;
    if (tid < 256) {
        float s = 0.0f;
        #pragma unroll
        for (int t = 0; t < 7; ++t) s += part2[((size_t)t * 64 + b) * 256 + tid];
        ps[tid] = s * (1.0f / 784.0f);
    }
    __syncthreads();
    {
        float acc = bh[tid];
        for (int i = 0; i < 256; ++i) acc = fmaf(ps[i], Wh[i * 512 + tid], acc);
        hs[tid] = acc;
    }
    __syncthreads();
    {
        int m = tid >> 4, part = tid & 15;
        int j0 = part * 32;
        float acc = 0.0f;
        #pragma unroll
        for (int jj = 0; jj < 32; ++jj) acc = fmaf(hs[j0 + jj], Wmu[(j0 + jj) * 32 + m], acc);
        red2[m * 16 + part] = acc;
    }
    if (tid < 16) {
        int j0 = tid * 32;
        float acc = 0.0f;
        #pragma unroll
        for (int jj = 0; jj < 32; ++jj) acc = fmaf(hs[j0 + jj], Wk[j0 + jj], acc);
        kred[tid] = acc;
    }
    __syncthreads();
    if (tid < 32) {
        float acc = bmu[tid];
        #pragma unroll
        for (int p = 0; p < 16; ++p) acc += red2[tid * 16 + p];
        ms[tid] = acc;
    }
    if (tid == 32) {
        float acc = bk[0];
        #pragma unroll
        for (int p = 0; p < 16; ++p) acc += kred[p];
        float sp = fmaxf(acc, 0.0f) + log1pf(expf(-fabsf(acc)));
        out[2496 + b] = sp + 1.0f;
    }
    __syncthreads();
    if (tid == 0) {
        float ss = 0.0f;
        for (int k = 0; k < 32; ++k) ss += ms[k] * ms[k];
        nrm = sqrtf(fmaxf(ss, 1e-24f));
    }
    __syncthreads();
    if (tid < 32) out[448 + b * 32 + tid] = ms[tid] / nrm;
}

// ---------------- Wood vMF sampling (JAX threefry bit-exact) ----------------
__global__ __launch_bounds__(64) void vmf_sample(const float* __restrict__ mu,
                                                 const float* __restrict__ kap,
                                                 float* __restrict__ z) {
    int b = threadIdx.x;
    if (b >= 64) return;

    uint32_t kw0, kw1, kv0, kv1;
    {
        uint32_t y00, y01, y10, y11;
        threefry2x32(0u, 42u, 0u, 2u, y00, y01);
        threefry2x32(0u, 42u, 1u, 3u, y10, y11);
        kw0 = y00; kw1 = y10;
        kv0 = y01; kv1 = y11;
    }

    float kappa = kap[b];
    float w = 0.0f;
    bool accepted = false;
    uint32_t p = (uint32_t)(b & 31);
    #pragma unroll 1
    for (int i = 0; i < 10; i++) {
        uint32_t k10, k11, k20, k21, y0, y1;
        threefry2x32(kw0, kw1, 0u, (uint32_t)(2 * i), k10, k11);
        threefry2x32(kw0, kw1, 0u, (uint32_t)(2 * i + 1), k20, k21);
        threefry2x32(k10, k11, p, 32u + p, y0, y1);
        uint32_t bits = (b < 32) ? y0 : y1;
        float u1 = bits_to_unit_float(bits);
        float wc = 2.0f * u1 - 1.0f;
        float om = fmaxf(1.0f - wc * wc, 1e-40f);
        float logp = kappa * wc + 14.5f * logf(om);
        threefry2x32(k20, k21, p, 32u + p, y0, y1);
        bits = (b < 32) ? y0 : y1;
        float u2 = bits_to_unit_float(bits);
        float logr = logf(u2 + 1e-40f);
        bool newly = (logr + kappa <= logp) && !accepted;
        if (newly) w = wc;
        accepted = accepted || newly;
    }
    w = fminf(fmaxf(w, -1.0f), 1.0f);

    float v[31];
    float ss = 0.0f;
    const float LO = -0.99999994f;
    #pragma unroll 1
    for (int j = 0; j < 31; j++) {
        int idx = b * 31 + j;
        int word = (idx >= 992);
        uint32_t pp = (uint32_t)(word ? idx - 992 : idx);
        uint32_t y0, y1;
        threefry2x32(kv0, kv1, pp, 992u + pp, y0, y1);
        uint32_t bits = word ? y1 : y0;
        float f = bits_to_unit_float(bits);
        float u = fmaxf(LO, f * 2.0f + LO);
        float val = 1.41421356f * erfinv_f(u);
        v[j] = val;
        ss += val * val;
    }
    float vinv = 1.0f / sqrtf(fmaxf(ss, 1e-24f));
    float st = sqrtf(fmaxf(1.0f - w * w, 1e-40f));

    float zt[32];
    #pragma unroll
    for (int j = 0; j < 31; j++) zt[j] = st * (v[j] * vinv);
    zt[31] = w;

    float uv[32];
    float us = 0.0f;
    #pragma unroll
    for (int k = 0; k < 32; k++) {
        float m = mu[b * 32 + k];
        float e = (k == 31) ? 1.0f : 0.0f;
        float t = e - m;
        uv[k] = t;
        us += t * t;
    }
    float un = sqrtf(fmaxf(us, 1e-24f));
    float dot = 0.0f;
    #pragma unroll
    for (int k = 0; k < 32; k++) {
        uv[k] = uv[k] / un;
        dot += zt[k] * uv[k];
    }
    #pragma unroll
    for (int k = 0; k < 32; k++) z[b * 32 + k] = zt[k] - 2.0f * dot * uv[k];
}

// ---------------- MLP head (32->512->512->32->7) ----------------
__global__ __launch_bounds__(512) void mlp_head(const float* __restrict__ z,
                                                const float* __restrict__ M1, const float* __restrict__ bM1,
                                                const float* __restrict__ M2, const float* __restrict__ bM2,
                                                const float* __restrict__ M3, const float* __restrict__ bM3,
                                                const float* __restrict__ M4, const float* __restrict__ bM4,
                                                float* __restrict__ out) {
    int b = blockIdx.x;
    int tid = threadIdx.x;
    __shared__ float zs[32], y1[512], y2[512], y3[32];
    if (tid < 32) zs[tid] = z[b * 32 + tid];
    __syncthreads();
    float acc = bM1[tid];
    #pragma unroll
    for (int k = 0; k < 32; k++) acc = fmaf(zs[k], M1[k * 512 + tid], acc);
    y1[tid] = fmaxf(acc, 0.0f);
    __syncthreads();
    acc = bM2[tid];
    for (int k = 0; k < 512; k++) acc = fmaf(y1[k], M2[k * 512 + tid], acc);
    y2[tid] = fmaxf(acc, 0.0f);
    __syncthreads();
    if (tid < 32) {
        acc = bM3[tid];
        for (int k = 0; k < 512; k++) acc = fmaf(y2[k], M3[k * 32 + tid], acc);
        y3[tid] = fmaxf(acc, 0.0f);
    }
    __syncthreads();
    if (tid < 7) {
        acc = bM4[tid];
        #pragma unroll
        for (int k = 0; k < 32; k++) acc = fmaf(y3[k], M4[k * 7 + tid], acc);
        out[b * 7 + tid] = acc;
    }
}

extern "C" void kernel_launch(void* const* d_in, const int* in_sizes, int n_in,
                              void* d_out, int out_size, void* d_ws, size_t ws_size,
                              hipStream_t stream) {
    const float* x   = (const float*)d_in[0];
    const float* W1  = (const float*)d_in[1];
    const float* b1  = (const float*)d_in[2];
    const float* W2  = (const float*)d_in[3];
    const float* b2  = (const float*)d_in[4];
    const float* Wh  = (const float*)d_in[5];
    const float* bh  = (const float*)d_in[6];
    const float* Wmu = (const float*)d_in[7];
    const float* bmu = (const float*)d_in[8];
    const float* Wk  = (const float*)d_in[9];
    const float* bk  = (const float*)d_in[10];
    const float* M1  = (const float*)d_in[11];
    const float* bM1 = (const float*)d_in[12];
    const float* M2  = (const float*)d_in[13];
    const float* bM2 = (const float*)d_in[14];
    const float* M3  = (const float*)d_in[15];
    const float* bM3 = (const float*)d_in[16];
    const float* M4  = (const float*)d_in[17];
    const float* bM4 = (const float*)d_in[18];

    float* out = (float*)d_out;
    float* ws  = (float*)d_ws;

    // workspace layout (floats)
    float* W2T   = ws;                   // 147456
    float* c1    = W2T + 147456;         // 12845056
    float* part2 = c1 + 12845056;        // 7*64*256 = 114688
    float* z     = part2 + 114688;       // 2048

    transpose_W2<<<144, 256, 0, stream>>>(W2, W2T);
    conv1_tiled<<<896, 256, 0, stream>>>(x, W1, b1, c1);
    conv2_tiled<<<896, 256, 0, stream>>>(c1, W2T, b2, part2);
    head_fused<<<64, 512, 0, stream>>>(part2, Wh, bh, Wmu, bmu, Wk, bk, out);
    vmf_sample<<<1, 64, 0, stream>>>(out + 448, out + 2496, z);
    mlp_head<<<64, 512, 0, stream>>>(z, M1, bM1, M2, bM2, M3, bM3, M4, bM4, out);
}